// Round 1
// baseline (249.483 us; speedup 1.0000x reference)
//
#include <hip/hip_runtime.h>
#include <math.h>

static constexpr int Nb = 32;    // batch
static constexpr int Cc = 512;   // channels
static constexpr int Ss = 1024;  // spatial
static constexpr int Kk = 64;    // clusters
static constexpr int Dd = 256;   // out dim

// ---------------------------------------------------------------------------
// K1: fused per-(n, s-tile of 64): raw conv dots + sum(x^2) over C during
// staging -> inv_norm, scale, softmax over K, write a[n][k][s] and inv_norm.
// grid (16, 32), block 256.
// ---------------------------------------------------------------------------
__global__ __launch_bounds__(256) void k1_sa(
    const float* __restrict__ x, const float* __restrict__ conv_w,
    float* __restrict__ a_out, float* __restrict__ inv_norm)
{
    __shared__ float xs[64][68];     // [c_local][s_local], raw x
    __shared__ float cwt[64][68];    // [c_local][k]
    __shared__ float sa_l[64][68];   // [k][s_local]
    __shared__ float red[4][64];
    __shared__ float invn_l[64];
    __shared__ float row_stat[64];

    const int tid = threadIdx.x;
    const int n   = blockIdx.y;
    const int s0  = blockIdx.x * 64;
    const int kq  = tid >> 4;   // 0..15 -> k = kq*4+ki
    const int sq  = tid & 15;   // 0..15 -> s = sq*4+si

    float acc[4][4];
#pragma unroll
    for (int i = 0; i < 4; ++i)
#pragma unroll
        for (int j = 0; j < 4; ++j) acc[i][j] = 0.f;

    float ssq = 0.f;  // partial sum x^2 for s_local = tid&63

    for (int c0 = 0; c0 < Cc; c0 += 64) {
        __syncthreads();
#pragma unroll
        for (int i = 0; i < 16; ++i) {
            int idx = tid + i * 256;
            int cl = idx >> 6, sl = idx & 63;
            float v = x[((size_t)n * Cc + (c0 + cl)) * Ss + s0 + sl];
            xs[cl][sl] = v;
            ssq += v * v;              // sl == tid&63 for every i
        }
#pragma unroll
        for (int i = 0; i < 16; ++i) {
            int idx = tid + i * 256;
            int k = idx >> 6, cl = idx & 63;
            cwt[cl][k] = conv_w[k * Cc + c0 + cl];
        }
        __syncthreads();
#pragma unroll 8
        for (int cl = 0; cl < 64; ++cl) {
            const float4 cv = *(const float4*)&cwt[cl][kq * 4];
            const float4 xv = *(const float4*)&xs[cl][sq * 4];
            acc[0][0] += cv.x * xv.x; acc[0][1] += cv.x * xv.y;
            acc[0][2] += cv.x * xv.z; acc[0][3] += cv.x * xv.w;
            acc[1][0] += cv.y * xv.x; acc[1][1] += cv.y * xv.y;
            acc[1][2] += cv.y * xv.z; acc[1][3] += cv.y * xv.w;
            acc[2][0] += cv.z * xv.x; acc[2][1] += cv.z * xv.y;
            acc[2][2] += cv.z * xv.z; acc[2][3] += cv.z * xv.w;
            acc[3][0] += cv.w * xv.x; acc[3][1] += cv.w * xv.y;
            acc[3][2] += cv.w * xv.z; acc[3][3] += cv.w * xv.w;
        }
    }

    // reduce sum(x^2) across the 4 thread-groups per s
    red[tid >> 6][tid & 63] = ssq;
    __syncthreads();
    if (tid < 64) {
        float t = red[0][tid] + red[1][tid] + red[2][tid] + red[3][tid];
        float inv = 1.f / fmaxf(sqrtf(t), 1e-12f);
        invn_l[tid] = inv;
        inv_norm[n * Ss + s0 + tid] = inv;
    }
    __syncthreads();

    // scaled scores into LDS
#pragma unroll
    for (int ki = 0; ki < 4; ++ki)
#pragma unroll
        for (int si = 0; si < 4; ++si)
            sa_l[kq * 4 + ki][sq * 4 + si] = acc[ki][si] * invn_l[sq * 4 + si];
    __syncthreads();

    // softmax over k (64) per s
    const int kg = tid >> 6;     // 0..3
    const int s  = tid & 63;
    float mp = -1e30f;
#pragma unroll
    for (int i = 0; i < 16; ++i) mp = fmaxf(mp, sa_l[kg * 16 + i][s]);
    red[kg][s] = mp;
    __syncthreads();
    if (tid < 64)
        row_stat[tid] = fmaxf(fmaxf(red[0][tid], red[1][tid]),
                              fmaxf(red[2][tid], red[3][tid]));
    __syncthreads();
    float m = row_stat[s];
    float sp = 0.f;
#pragma unroll
    for (int i = 0; i < 16; ++i) {
        int k = kg * 16 + i;
        float e = expf(sa_l[k][s] - m);
        sa_l[k][s] = e;
        sp += e;
    }
    red[kg][s] = sp;
    __syncthreads();
    if (tid < 64)
        row_stat[tid] = 1.f / (red[0][tid] + red[1][tid] + red[2][tid] + red[3][tid]);
    __syncthreads();

#pragma unroll
    for (int i = 0; i < 16; ++i) {
        int idx = tid + i * 256;
        int k = idx >> 6, s2 = idx & 63;
        a_out[((size_t)n * Kk + k) * Ss + s0 + s2] = sa_l[k][s2] * row_stat[s2];
    }
}

// ---------------------------------------------------------------------------
// K2: vlad[n][k][c] = sum_s a[n][k][s] * xn[n][c][s] - asum[n][k]*cent[k][c]
// per (n, c-slice of 64). asum computed for free during a staging.
// grid (32, 8), block 256.  (n fast in blockIdx -> same-n blocks share XCD L2)
// ---------------------------------------------------------------------------
__global__ __launch_bounds__(256) void k2_vlad(
    const float* __restrict__ x, const float* __restrict__ a,
    const float* __restrict__ inv_norm, const float* __restrict__ centroids,
    float* __restrict__ vlad)
{
    __shared__ float a_t[32][68];    // [s][k]
    __shared__ float xn_t[32][68];   // [s][c_local]
    __shared__ float asum_l[64];

    const int tid = threadIdx.x;
    const int n   = blockIdx.x;
    const int c0  = blockIdx.y * 64;
    const int kq  = tid >> 4;   // 0..15
    const int cq  = tid & 15;   // 0..15

    float acc[4][4];
#pragma unroll
    for (int i = 0; i < 4; ++i)
#pragma unroll
        for (int j = 0; j < 4; ++j) acc[i][j] = 0.f;
    float asump[8];
#pragma unroll
    for (int i = 0; i < 8; ++i) asump[i] = 0.f;

    for (int sc = 0; sc < Ss; sc += 32) {
        float invv = inv_norm[n * Ss + sc + (tid & 31)];
        __syncthreads();
#pragma unroll
        for (int i = 0; i < 8; ++i) {
            int idx = tid + i * 256;
            int r = idx >> 5, s = idx & 31;        // r: 0..63 (k row / c row)
            float av = a[((size_t)n * Kk + r) * Ss + sc + s];
            a_t[s][r] = av;
            asump[i] += av;
            float xv = x[((size_t)n * Cc + (c0 + r)) * Ss + sc + s] * invv;
            xn_t[s][r] = xv;
        }
        __syncthreads();
#pragma unroll 4
        for (int s = 0; s < 32; ++s) {
            const float4 av = *(const float4*)&a_t[s][kq * 4];
            const float4 xv = *(const float4*)&xn_t[s][cq * 4];
            acc[0][0] += av.x * xv.x; acc[0][1] += av.x * xv.y;
            acc[0][2] += av.x * xv.z; acc[0][3] += av.x * xv.w;
            acc[1][0] += av.y * xv.x; acc[1][1] += av.y * xv.y;
            acc[1][2] += av.y * xv.z; acc[1][3] += av.y * xv.w;
            acc[2][0] += av.z * xv.x; acc[2][1] += av.z * xv.y;
            acc[2][2] += av.z * xv.z; acc[2][3] += av.z * xv.w;
            acc[3][0] += av.w * xv.x; acc[3][1] += av.w * xv.y;
            acc[3][2] += av.w * xv.z; acc[3][3] += av.w * xv.w;
        }
    }

    // asum[k] for k = tid/32 + 8i : reduce over the 32 s-lanes
#pragma unroll
    for (int i = 0; i < 8; ++i) {
        float v = asump[i];
        for (int off = 16; off >= 1; off >>= 1) v += __shfl_xor(v, off);
        if ((tid & 31) == 0) asum_l[(tid >> 5) + 8 * i] = v;
    }
    __syncthreads();

#pragma unroll
    for (int ki = 0; ki < 4; ++ki) {
        int k = kq * 4 + ki;
        float as = asum_l[k];
        const float4 ce = *(const float4*)&centroids[(size_t)k * Cc + c0 + cq * 4];
        float4 o;
        o.x = acc[ki][0] - as * ce.x;
        o.y = acc[ki][1] - as * ce.y;
        o.z = acc[ki][2] - as * ce.z;
        o.w = acc[ki][3] - as * ce.w;
        *(float4*)&vlad[((size_t)n * Kk + k) * Cc + c0 + cq * 4] = o;
    }
}

// ---------------------------------------------------------------------------
// K3: per-(n,k) intra-norm + per-n global norm -> scale[n][k]
// grid 32, block 512 (64 k * 8 lanes)
// ---------------------------------------------------------------------------
__global__ __launch_bounds__(512) void k3_scale(
    const float* __restrict__ vlad, float* __restrict__ scale)
{
    __shared__ float nrm_l[64];
    const int tid = threadIdx.x, n = blockIdx.x;
    const int k = tid >> 3, u = tid & 7;
    const float* vp = &vlad[((size_t)n * Kk + k) * Cc];
    float ssq = 0.f;
#pragma unroll 8
    for (int j = 0; j < 64; ++j) {
        float v = vp[u + 8 * j];
        ssq += v * v;
    }
    ssq += __shfl_xor(ssq, 1);
    ssq += __shfl_xor(ssq, 2);
    ssq += __shfl_xor(ssq, 4);
    if (u == 0) nrm_l[k] = sqrtf(ssq);
    __syncthreads();
    if (tid < 64) {
        float r = nrm_l[tid];
        float rn = r / fmaxf(r, 1e-12f);
        float p = rn * rn;
        for (int off = 32; off >= 1; off >>= 1) p += __shfl_xor(p, off);
        float g = sqrtf(p);
        scale[n * Kk + tid] = 1.f / (fmaxf(r, 1e-12f) * fmaxf(g, 1e-12f));
    }
}

// ---------------------------------------------------------------------------
// K4: partial v[n][d] over a kc-chunk of 128: vpart[chunk][n][d]
// grid 256, block 256. thread: dq = tid&63 (4 d's), nq = tid>>6 (8 n's)
// ---------------------------------------------------------------------------
__global__ __launch_bounds__(256) void k4_hidden(
    const float* __restrict__ vlad, const float* __restrict__ scale,
    const float* __restrict__ hw, float* __restrict__ vpart)
{
    __shared__ float vl[128][36];
    __shared__ float scale_l[32];
    const int tid = threadIdx.x;
    const int kc0 = blockIdx.x * 128;
    const int k = kc0 >> 9;             // chunk lies inside one k
    if (tid < 32) scale_l[tid] = scale[tid * Kk + k];
    __syncthreads();
#pragma unroll
    for (int i = 0; i < 16; ++i) {
        int idx = tid + i * 256;
        int nn = idx >> 7, kcl = idx & 127;
        vl[kcl][nn] = vlad[(size_t)nn * (Kk * Cc) + kc0 + kcl] * scale_l[nn];
    }
    __syncthreads();

    const int dq = tid & 63, nq = tid >> 6;
    float acc[4][8];
#pragma unroll
    for (int i = 0; i < 4; ++i)
#pragma unroll
        for (int j = 0; j < 8; ++j) acc[i][j] = 0.f;

    for (int kcl = 0; kcl < 128; ++kcl) {
        const float4 v0 = *(const float4*)&vl[kcl][nq * 8];
        const float4 v1 = *(const float4*)&vl[kcl][nq * 8 + 4];
        const float* wrow = &hw[(size_t)(kc0 + kcl) * Dd + dq];
#pragma unroll
        for (int dd = 0; dd < 4; ++dd) {
            float w = wrow[64 * dd];
            acc[dd][0] += w * v0.x; acc[dd][1] += w * v0.y;
            acc[dd][2] += w * v0.z; acc[dd][3] += w * v0.w;
            acc[dd][4] += w * v1.x; acc[dd][5] += w * v1.y;
            acc[dd][6] += w * v1.z; acc[dd][7] += w * v1.w;
        }
    }
#pragma unroll
    for (int dd = 0; dd < 4; ++dd)
#pragma unroll
        for (int j = 0; j < 8; ++j)
            vpart[((size_t)blockIdx.x * Nb + nq * 8 + j) * Dd + dq + 64 * dd] = acc[dd][j];
}

// ---------------------------------------------------------------------------
// K5a: reduce 256 partial chunks -> v[n][d].  grid 32, block 256.
// ---------------------------------------------------------------------------
__global__ __launch_bounds__(256) void k5a_reduce(
    const float* __restrict__ vpart, float* __restrict__ v)
{
    int flat = blockIdx.x * 256 + threadIdx.x;
    float s = 0.f;
#pragma unroll 8
    for (int ch = 0; ch < 256; ++ch) s += vpart[(size_t)ch * (Nb * Dd) + flat];
    v[flat] = s;
}

// ---------------------------------------------------------------------------
// K5b: BatchNorm over n (training stats, biased var, exact two-pass)
// grid 1, block 256 (one thread per d)
// ---------------------------------------------------------------------------
__global__ __launch_bounds__(256) void k5b_bn(
    const float* __restrict__ v, const float* __restrict__ gamma,
    const float* __restrict__ beta, float* __restrict__ v_bn)
{
    const int d = threadIdx.x;
    float vals[Nb];
    float s1 = 0.f;
#pragma unroll
    for (int n = 0; n < Nb; ++n) {
        vals[n] = v[n * Dd + d];
        s1 += vals[n];
    }
    float m = s1 * (1.f / Nb);
    float var = 0.f;
#pragma unroll
    for (int n = 0; n < Nb; ++n) {
        float t = vals[n] - m;
        var += t * t;
    }
    var *= (1.f / Nb);
    float inv = rsqrtf(var + 1e-5f);
    float g = gamma[d], b = beta[d];
#pragma unroll
    for (int n = 0; n < Nb; ++n)
        v_bn[n * Dd + d] = (vals[n] - m) * inv * g + b;
}

// ---------------------------------------------------------------------------
// K5c: g_raw = v_bn @ gating_w.  grid 32 (n), block 256 (d)
// ---------------------------------------------------------------------------
__global__ __launch_bounds__(256) void k5c_gate(
    const float* __restrict__ v_bn, const float* __restrict__ gw,
    float* __restrict__ g_raw)
{
    __shared__ float vb[Dd];
    const int n = blockIdx.x, d = threadIdx.x;
    vb[d] = v_bn[n * Dd + d];
    __syncthreads();
    float acc = 0.f;
#pragma unroll 8
    for (int c = 0; c < Dd; ++c) acc += vb[c] * gw[c * Dd + d];
    g_raw[n * Dd + d] = acc;
}

// ---------------------------------------------------------------------------
// K5d: gbn BatchNorm + sigmoid + multiply -> out.  grid 1, block 256.
// ---------------------------------------------------------------------------
__global__ __launch_bounds__(256) void k5d_out(
    const float* __restrict__ g_raw, const float* __restrict__ v_bn,
    const float* __restrict__ ggamma, const float* __restrict__ gbeta,
    float* __restrict__ out)
{
    const int d = threadIdx.x;
    float vals[Nb];
    float s1 = 0.f;
#pragma unroll
    for (int n = 0; n < Nb; ++n) {
        vals[n] = g_raw[n * Dd + d];
        s1 += vals[n];
    }
    float m = s1 * (1.f / Nb);
    float var = 0.f;
#pragma unroll
    for (int n = 0; n < Nb; ++n) {
        float t = vals[n] - m;
        var += t * t;
    }
    var *= (1.f / Nb);
    float inv = rsqrtf(var + 1e-5f);
    float g = ggamma[d], b = gbeta[d];
#pragma unroll
    for (int n = 0; n < Nb; ++n) {
        float t = (vals[n] - m) * inv * g + b;
        float sg = 1.f / (1.f + expf(-t));
        out[n * Dd + d] = v_bn[n * Dd + d] * sg;
    }
}

// ---------------------------------------------------------------------------
extern "C" void kernel_launch(void* const* d_in, const int* in_sizes, int n_in,
                              void* d_out, int out_size, void* d_ws, size_t ws_size,
                              hipStream_t stream)
{
    const float* x         = (const float*)d_in[0];
    const float* conv_w    = (const float*)d_in[1];
    const float* centroids = (const float*)d_in[2];
    const float* hidden_w  = (const float*)d_in[3];
    const float* bn2_gamma = (const float*)d_in[4];
    const float* bn2_beta  = (const float*)d_in[5];
    const float* gating_w  = (const float*)d_in[6];
    const float* gbn_gamma = (const float*)d_in[7];
    const float* gbn_beta  = (const float*)d_in[8];
    float* out = (float*)d_out;

    float* w = (float*)d_ws;
    float* a        = w;                  // 2,097,152 f  (aliased by vpart later)
    float* vlad     = w + 2097152;        // 1,048,576 f
    float* inv_norm = w + 3145728;        //    32,768 f
    float* scale    = w + 3178496;        //     2,048 f
    float* v        = w + 3180544;        //     8,192 f
    float* v_bn     = w + 3188736;        //     8,192 f
    float* g_raw    = w + 3196928;        //     8,192 f
    float* vpart    = a;                  // reuse: a is dead after k2

    k1_sa<<<dim3(16, 32), 256, 0, stream>>>(x, conv_w, a, inv_norm);
    k2_vlad<<<dim3(32, 8), 256, 0, stream>>>(x, a, inv_norm, centroids, vlad);
    k3_scale<<<32, 512, 0, stream>>>(vlad, scale);
    k4_hidden<<<256, 256, 0, stream>>>(vlad, scale, hidden_w, vpart);
    k5a_reduce<<<32, 256, 0, stream>>>(vpart, v);
    k5b_bn<<<1, 256, 0, stream>>>(v, bn2_gamma, bn2_beta, v_bn);
    k5c_gate<<<32, 256, 0, stream>>>(v_bn, gating_w, g_raw);
    k5d_out<<<1, 256, 0, stream>>>(g_raw, v_bn, gbn_gamma, gbn_beta, out);
}

// Round 2
// 155.667 us; speedup vs baseline: 1.6027x; 1.6027x over previous
//
#include <hip/hip_runtime.h>
#include <math.h>

static constexpr int Nb = 32;    // batch
static constexpr int Cc = 512;   // channels
static constexpr int Ss = 1024;  // spatial
static constexpr int Kk = 64;    // clusters
static constexpr int Dd = 256;   // out dim

// ---------------------------------------------------------------------------
// K1: per-(s-tile of 64, n): conv scores (sum over C=512 in 8 LDS tiles),
// fused sum(x^2) during staging -> inv_norm, softmax over K=64, writes
// a[n][k][s], inv_norm[n][s], asum_part[n][k][stile].
// grid (16 stiles, 32 n), block 512 (8 waves) -> 2 blocks/CU, 16 waves/CU.
// ---------------------------------------------------------------------------
__global__ __launch_bounds__(512) void k1_sa(
    const float* __restrict__ x, const float* __restrict__ conv_w,
    float* __restrict__ a_out, float* __restrict__ inv_norm,
    float* __restrict__ asum_part)
{
    __shared__ float xs[64][72];    // [c][s] staging of x; reused as sa_l[k][s]
    __shared__ float cwt[64][68];   // [c][k] transposed conv_w
    __shared__ float redsq[32][68]; // per-c-group sum(x^2) partials
    __shared__ float redm[8][68];
    __shared__ float reds[8][68];
    __shared__ float invn_l[64];

    const int tid = threadIdx.x;
    const int s0  = blockIdx.x * 64;
    const int n   = blockIdx.y;

    const int kq = tid >> 5;        // 0..15 -> k = kq*4+ki
    const int sq = tid & 31;        // 0..31 -> s = sq*2+si

    // staging maps
    const int cs_c = tid >> 4;      // 0..31
    const int cs_f = tid & 15;      // 0..15 (f4 column over 64 s)
    const int cw_k = tid >> 3;      // 0..63
    const int cw_f = tid & 7;       // 0..7

    float acc[4][2] = {{0.f,0.f},{0.f,0.f},{0.f,0.f},{0.f,0.f}};
    float4 ssq4 = {0.f,0.f,0.f,0.f};

    for (int c0 = 0; c0 < Cc; c0 += 64) {
        __syncthreads();
        // stage x [64c][64s] as float4 + accumulate x^2 per s
#pragma unroll
        for (int rep = 0; rep < 2; ++rep) {
            int c = cs_c + 32 * rep;
            float4 v = *(const float4*)&x[((size_t)(n * Cc + c0 + c)) * Ss + s0 + 4 * cs_f];
            ssq4.x += v.x * v.x; ssq4.y += v.y * v.y;
            ssq4.z += v.z * v.z; ssq4.w += v.w * v.w;
            *(float4*)&xs[c][4 * cs_f] = v;
        }
        // stage conv_w transposed: cwt[c][k]
#pragma unroll
        for (int rep = 0; rep < 2; ++rep) {
            int cf = cw_f + 8 * rep;
            float4 v = *(const float4*)&conv_w[(size_t)cw_k * Cc + c0 + 4 * cf];
            cwt[4 * cf + 0][cw_k] = v.x;
            cwt[4 * cf + 1][cw_k] = v.y;
            cwt[4 * cf + 2][cw_k] = v.z;
            cwt[4 * cf + 3][cw_k] = v.w;
        }
        __syncthreads();
#pragma unroll 8
        for (int cl = 0; cl < 64; ++cl) {
            const float4 cv = *(const float4*)&cwt[cl][kq * 4];
            const float2 xv = *(const float2*)&xs[cl][sq * 2];
            acc[0][0] += cv.x * xv.x; acc[0][1] += cv.x * xv.y;
            acc[1][0] += cv.y * xv.x; acc[1][1] += cv.y * xv.y;
            acc[2][0] += cv.z * xv.x; acc[2][1] += cv.z * xv.y;
            acc[3][0] += cv.w * xv.x; acc[3][1] += cv.w * xv.y;
        }
    }

    // reduce sum(x^2): 32 c-groups -> per-s total
    __syncthreads();
    *(float4*)&redsq[cs_c][4 * cs_f] = ssq4;
    __syncthreads();
    if (tid < 64) {
        float t = 0.f;
#pragma unroll
        for (int g = 0; g < 32; ++g) t += redsq[g][tid];
        float inv = 1.f / fmaxf(sqrtf(t), 1e-12f);
        invn_l[tid] = inv;
        inv_norm[n * Ss + s0 + tid] = inv;
    }
    __syncthreads();

    // scaled scores into LDS (reuse xs as sa_l[k][s], stride 72)
    {
        float i0 = invn_l[sq * 2], i1 = invn_l[sq * 2 + 1];
#pragma unroll
        for (int ki = 0; ki < 4; ++ki) {
            xs[kq * 4 + ki][sq * 2]     = acc[ki][0] * i0;
            xs[kq * 4 + ki][sq * 2 + 1] = acc[ki][1] * i1;
        }
    }
    __syncthreads();

    // softmax over k (64) per s; thread owns 8 k's for one s
    const int ss = tid & 63;
    const int kg = tid >> 6;        // 0..7
    float m8 = -1e30f;
#pragma unroll
    for (int i = 0; i < 8; ++i) m8 = fmaxf(m8, xs[kg * 8 + i][ss]);
    redm[kg][ss] = m8;
    __syncthreads();
    float m = redm[0][ss];
#pragma unroll
    for (int j = 1; j < 8; ++j) m = fmaxf(m, redm[j][ss]);
    float sp = 0.f;
#pragma unroll
    for (int i = 0; i < 8; ++i) {
        float e = expf(xs[kg * 8 + i][ss] - m);
        xs[kg * 8 + i][ss] = e;
        sp += e;
    }
    reds[kg][ss] = sp;
    __syncthreads();
    float den = reds[0][ss];
#pragma unroll
    for (int j = 1; j < 8; ++j) den += reds[j][ss];
    float rinv = 1.f / den;

    // write a + per-(k, s-tile) sums (for the centroid term)
#pragma unroll
    for (int i = 0; i < 8; ++i) {
        int k = kg + 8 * i;                       // uniform per wave
        float val = xs[k][ss] * rinv;
        a_out[((size_t)(n * Kk + k)) * Ss + s0 + ss] = val;
        float asv = val;
#pragma unroll
        for (int off = 32; off >= 1; off >>= 1) asv += __shfl_xor(asv, off);
        if ((tid & 63) == 0) asum_part[((n * Kk + k) << 4) + blockIdx.x] = asv;
    }
}

// ---------------------------------------------------------------------------
// K2: vlad[n][k][c] = sum_s a[n][k][s]*xn[n][c][s] - asum[n][k]*cent[k][c]
// tile 64k x 32c per block; grid (32 n, 16 ct) = 512 blocks -> 2 blocks/CU.
// Double-buffered LDS with reg-staged prefetch (64-s tiles).
// blockIdx.x = n keeps same-n blocks on one XCD (L2 reuse of a).
// ---------------------------------------------------------------------------
__global__ __launch_bounds__(256) void k2_vlad(
    const float* __restrict__ x, const float* __restrict__ a,
    const float* __restrict__ inv_norm, const float* __restrict__ centroids,
    const float* __restrict__ asum_part, float* __restrict__ vlad)
{
    __shared__ float a_t[2][64][68];   // [buf][s][k]  (raw a, transposed)
    __shared__ float xn_t[2][64][36];  // [buf][s][c_local] (x * inv_norm)
    __shared__ float asum_l[64];

    const int tid = threadIdx.x;
    const int n   = blockIdx.x;
    const int c0  = blockIdx.y * 32;

    const int kq = tid >> 4;   // 0..15 -> 4 k's
    const int cq = tid & 15;   // 0..15 -> 2 c's

    if (tid < 64) {
        float s = 0.f;
#pragma unroll
        for (int st = 0; st < 16; ++st) s += asum_part[((n * Kk + tid) << 4) + st];
        asum_l[tid] = s;
    }

    const int sa_r = tid >> 3;   // 0..31
    const int sa_f = tid & 7;    // 0..7

    float4 ra[4], rx[2], ri[2];

    auto LOADT = [&](int t) {
        const int sb = t * 64;
#pragma unroll
        for (int rep = 0; rep < 4; ++rep) {
            int r = sa_r + 32 * (rep & 1);
            int f = sa_f + 8 * (rep >> 1);
            ra[rep] = *(const float4*)&a[((size_t)(n * Kk + r)) * Ss + sb + 4 * f];
        }
#pragma unroll
        for (int rep = 0; rep < 2; ++rep) {
            int f = sa_f + 8 * rep;
            rx[rep] = *(const float4*)&x[((size_t)(n * Cc + c0 + sa_r)) * Ss + sb + 4 * f];
            ri[rep] = *(const float4*)&inv_norm[n * Ss + sb + 4 * f];
        }
    };
    auto STORET = [&](int b) {
#pragma unroll
        for (int rep = 0; rep < 4; ++rep) {
            int r = sa_r + 32 * (rep & 1);
            int f = sa_f + 8 * (rep >> 1);
            a_t[b][4 * f + 0][r] = ra[rep].x;
            a_t[b][4 * f + 1][r] = ra[rep].y;
            a_t[b][4 * f + 2][r] = ra[rep].z;
            a_t[b][4 * f + 3][r] = ra[rep].w;
        }
#pragma unroll
        for (int rep = 0; rep < 2; ++rep) {
            int f = sa_f + 8 * rep;
            xn_t[b][4 * f + 0][sa_r] = rx[rep].x * ri[rep].x;
            xn_t[b][4 * f + 1][sa_r] = rx[rep].y * ri[rep].y;
            xn_t[b][4 * f + 2][sa_r] = rx[rep].z * ri[rep].z;
            xn_t[b][4 * f + 3][sa_r] = rx[rep].w * ri[rep].w;
        }
    };

    float acc[4][2] = {{0.f,0.f},{0.f,0.f},{0.f,0.f},{0.f,0.f}};

    LOADT(0);
    STORET(0);
    __syncthreads();
    for (int t = 0; t < 16; ++t) {
        if (t + 1 < 16) LOADT(t + 1);       // prefetch into regs (hides HBM)
        const int b = t & 1;
#pragma unroll 8
        for (int s = 0; s < 64; ++s) {
            const float4 av = *(const float4*)&a_t[b][s][kq * 4];
            const float2 xv = *(const float2*)&xn_t[b][s][cq * 2];
            acc[0][0] += av.x * xv.x; acc[0][1] += av.x * xv.y;
            acc[1][0] += av.y * xv.x; acc[1][1] += av.y * xv.y;
            acc[2][0] += av.z * xv.x; acc[2][1] += av.z * xv.y;
            acc[3][0] += av.w * xv.x; acc[3][1] += av.w * xv.y;
        }
        __syncthreads();
        if (t + 1 < 16) STORET((t + 1) & 1);
        __syncthreads();
    }

#pragma unroll
    for (int ki = 0; ki < 4; ++ki) {
        int k = kq * 4 + ki;
        float as = asum_l[k];
        int c = c0 + cq * 2;
        const float2 ce = *(const float2*)&centroids[(size_t)k * Cc + c];
        float2 o;
        o.x = acc[ki][0] - as * ce.x;
        o.y = acc[ki][1] - as * ce.y;
        *(float2*)&vlad[((size_t)(n * Kk + k)) * Cc + c] = o;
    }
}

// ---------------------------------------------------------------------------
// K3: per-(n,k) intra-norm + per-n global norm -> scale[n][k]
// ---------------------------------------------------------------------------
__global__ __launch_bounds__(512) void k3_scale(
    const float* __restrict__ vlad, float* __restrict__ scale)
{
    __shared__ float nrm_l[64];
    const int tid = threadIdx.x, n = blockIdx.x;
    const int k = tid >> 3, u = tid & 7;
    const float* vp = &vlad[((size_t)n * Kk + k) * Cc];
    float ssq = 0.f;
#pragma unroll 8
    for (int j = 0; j < 64; ++j) {
        float v = vp[u + 8 * j];
        ssq += v * v;
    }
    ssq += __shfl_xor(ssq, 1);
    ssq += __shfl_xor(ssq, 2);
    ssq += __shfl_xor(ssq, 4);
    if (u == 0) nrm_l[k] = sqrtf(ssq);
    __syncthreads();
    if (tid < 64) {
        float r = nrm_l[tid];
        float rn = r / fmaxf(r, 1e-12f);
        float p = rn * rn;
        for (int off = 32; off >= 1; off >>= 1) p += __shfl_xor(p, off);
        float g = sqrtf(p);
        scale[n * Kk + tid] = 1.f / (fmaxf(r, 1e-12f) * fmaxf(g, 1e-12f));
    }
}

// ---------------------------------------------------------------------------
// K4: partial v[n][d] over a kc-chunk of 128: vpart[chunk][n][d]
// ---------------------------------------------------------------------------
__global__ __launch_bounds__(256) void k4_hidden(
    const float* __restrict__ vlad, const float* __restrict__ scale,
    const float* __restrict__ hw, float* __restrict__ vpart)
{
    __shared__ float vl[128][36];
    __shared__ float scale_l[32];
    const int tid = threadIdx.x;
    const int kc0 = blockIdx.x * 128;
    const int k = kc0 >> 9;             // chunk lies inside one k
    if (tid < 32) scale_l[tid] = scale[tid * Kk + k];
    __syncthreads();
#pragma unroll
    for (int i = 0; i < 16; ++i) {
        int idx = tid + i * 256;
        int nn = idx >> 7, kcl = idx & 127;
        vl[kcl][nn] = vlad[(size_t)nn * (Kk * Cc) + kc0 + kcl] * scale_l[nn];
    }
    __syncthreads();

    const int dq = tid & 63, nq = tid >> 6;
    float acc[4][8];
#pragma unroll
    for (int i = 0; i < 4; ++i)
#pragma unroll
        for (int j = 0; j < 8; ++j) acc[i][j] = 0.f;

    for (int kcl = 0; kcl < 128; ++kcl) {
        const float4 v0 = *(const float4*)&vl[kcl][nq * 8];
        const float4 v1 = *(const float4*)&vl[kcl][nq * 8 + 4];
        const float* wrow = &hw[(size_t)(kc0 + kcl) * Dd + dq];
#pragma unroll
        for (int dd = 0; dd < 4; ++dd) {
            float w = wrow[64 * dd];
            acc[dd][0] += w * v0.x; acc[dd][1] += w * v0.y;
            acc[dd][2] += w * v0.z; acc[dd][3] += w * v0.w;
            acc[dd][4] += w * v1.x; acc[dd][5] += w * v1.y;
            acc[dd][6] += w * v1.z; acc[dd][7] += w * v1.w;
        }
    }
#pragma unroll
    for (int dd = 0; dd < 4; ++dd)
#pragma unroll
        for (int j = 0; j < 8; ++j)
            vpart[((size_t)blockIdx.x * Nb + nq * 8 + j) * Dd + dq + 64 * dd] = acc[dd][j];
}

// ---------------------------------------------------------------------------
// K5a: reduce 256 partial chunks -> v[n][d]
// ---------------------------------------------------------------------------
__global__ __launch_bounds__(256) void k5a_reduce(
    const float* __restrict__ vpart, float* __restrict__ v)
{
    int flat = blockIdx.x * 256 + threadIdx.x;
    float s = 0.f;
#pragma unroll 8
    for (int ch = 0; ch < 256; ++ch) s += vpart[(size_t)ch * (Nb * Dd) + flat];
    v[flat] = s;
}

// ---------------------------------------------------------------------------
// K5b: BatchNorm over n (training stats, biased var, two-pass)
// ---------------------------------------------------------------------------
__global__ __launch_bounds__(256) void k5b_bn(
    const float* __restrict__ v, const float* __restrict__ gamma,
    const float* __restrict__ beta, float* __restrict__ v_bn)
{
    const int d = threadIdx.x;
    float vals[Nb];
    float s1 = 0.f;
#pragma unroll
    for (int n = 0; n < Nb; ++n) {
        vals[n] = v[n * Dd + d];
        s1 += vals[n];
    }
    float m = s1 * (1.f / Nb);
    float var = 0.f;
#pragma unroll
    for (int n = 0; n < Nb; ++n) {
        float t = vals[n] - m;
        var += t * t;
    }
    var *= (1.f / Nb);
    float inv = rsqrtf(var + 1e-5f);
    float g = gamma[d], b = beta[d];
#pragma unroll
    for (int n = 0; n < Nb; ++n)
        v_bn[n * Dd + d] = (vals[n] - m) * inv * g + b;
}

// ---------------------------------------------------------------------------
// K5c: g_raw = v_bn @ gating_w
// ---------------------------------------------------------------------------
__global__ __launch_bounds__(256) void k5c_gate(
    const float* __restrict__ v_bn, const float* __restrict__ gw,
    float* __restrict__ g_raw)
{
    __shared__ float vb[Dd];
    const int n = blockIdx.x, d = threadIdx.x;
    vb[d] = v_bn[n * Dd + d];
    __syncthreads();
    float acc = 0.f;
#pragma unroll 8
    for (int c = 0; c < Dd; ++c) acc += vb[c] * gw[c * Dd + d];
    g_raw[n * Dd + d] = acc;
}

// ---------------------------------------------------------------------------
// K5d: gbn BatchNorm + sigmoid + multiply -> out
// ---------------------------------------------------------------------------
__global__ __launch_bounds__(256) void k5d_out(
    const float* __restrict__ g_raw, const float* __restrict__ v_bn,
    const float* __restrict__ ggamma, const float* __restrict__ gbeta,
    float* __restrict__ out)
{
    const int d = threadIdx.x;
    float vals[Nb];
    float s1 = 0.f;
#pragma unroll
    for (int n = 0; n < Nb; ++n) {
        vals[n] = g_raw[n * Dd + d];
        s1 += vals[n];
    }
    float m = s1 * (1.f / Nb);
    float var = 0.f;
#pragma unroll
    for (int n = 0; n < Nb; ++n) {
        float t = vals[n] - m;
        var += t * t;
    }
    var *= (1.f / Nb);
    float inv = rsqrtf(var + 1e-5f);
    float g = ggamma[d], b = gbeta[d];
#pragma unroll
    for (int n = 0; n < Nb; ++n) {
        float t = (vals[n] - m) * inv * g + b;
        float sg = 1.f / (1.f + expf(-t));
        out[n * Dd + d] = v_bn[n * Dd + d] * sg;
    }
}

// ---------------------------------------------------------------------------
extern "C" void kernel_launch(void* const* d_in, const int* in_sizes, int n_in,
                              void* d_out, int out_size, void* d_ws, size_t ws_size,
                              hipStream_t stream)
{
    const float* x         = (const float*)d_in[0];
    const float* conv_w    = (const float*)d_in[1];
    const float* centroids = (const float*)d_in[2];
    const float* hidden_w  = (const float*)d_in[3];
    const float* bn2_gamma = (const float*)d_in[4];
    const float* bn2_beta  = (const float*)d_in[5];
    const float* gating_w  = (const float*)d_in[6];
    const float* gbn_gamma = (const float*)d_in[7];
    const float* gbn_beta  = (const float*)d_in[8];
    float* out = (float*)d_out;

    float* w = (float*)d_ws;
    float* a         = w;                  // 2,097,152 f (aliased by vpart later)
    float* vlad      = w + 2097152;        // 1,048,576 f
    float* inv_norm  = w + 3145728;        //    32,768 f
    float* asum_part = w + 3178496;        //    32,768 f
    float* scale     = w + 3211264;        //     2,048 f
    float* v         = w + 3213312;        //     8,192 f
    float* v_bn      = w + 3221504;        //     8,192 f
    float* g_raw     = w + 3229696;        //     8,192 f
    float* vpart     = a;                  // reuse: a is dead after k2

    k1_sa<<<dim3(16, 32), 512, 0, stream>>>(x, conv_w, a, inv_norm, asum_part);
    k2_vlad<<<dim3(32, 16), 256, 0, stream>>>(x, a, inv_norm, centroids, asum_part, vlad);
    k3_scale<<<32, 512, 0, stream>>>(vlad, scale);
    k4_hidden<<<256, 256, 0, stream>>>(vlad, scale, hidden_w, vpart);
    k5a_reduce<<<32, 256, 0, stream>>>(vpart, v);
    k5b_bn<<<1, 256, 0, stream>>>(v, bn2_gamma, bn2_beta, v_bn);
    k5c_gate<<<32, 256, 0, stream>>>(v_bn, gating_w, g_raw);
    k5d_out<<<1, 256, 0, stream>>>(g_raw, v_bn, gbn_gamma, gbn_beta, out);
}